// Round 13
// baseline (455.594 us; speedup 1.0000x reference)
//
#include <hip/hip_runtime.h>

#define N_NODES 100000
#define N_EDGES 20000
#define DIM 64
#define HEADS 4
#define NNZ_ 500000
#define LNEPS 1e-5f

__device__ __forceinline__ float wsum64(float v){
#pragma unroll
  for (int off = 32; off; off >>= 1) v += __shfl_xor(v, off);
  return v;
}
__device__ __forceinline__ float wmax64(float v){
#pragma unroll
  for (int off = 32; off; off >>= 1) v = fmaxf(v, __shfl_xor(v, off));
  return v;
}
__device__ __forceinline__ float lrelu2(float a){ return a > 0.f ? a : 0.2f*a; }

// pack 2 floats -> 2 bf16 (RNE) in one uint (a in low16, b in high16)
__device__ __forceinline__ unsigned bfpack(float a, float b){
  unsigned ua = __float_as_uint(a), ub = __float_as_uint(b);
  ua += 0x7fffu + ((ua >> 16) & 1u);
  ub += 0x7fffu + ((ub >> 16) & 1u);
  return (ua >> 16) | (ub & 0xffff0000u);
}
__device__ __forceinline__ unsigned short bf16of(float f){
  unsigned u = __float_as_uint(f);
  u += 0x7fffu + ((u >> 16) & 1u);
  return (unsigned short)(u >> 16);
}
__device__ __forceinline__ float bfup(unsigned short s){
  return __uint_as_float(((unsigned)s) << 16);
}
// extract head-H alpha from packed metadata {e, bfpack(a0,a1), bfpack(a2,a3)}
__device__ __forceinline__ float alphaOf(const int4& m, int H){
  unsigned u = (H < 2) ? (unsigned)m.y : (unsigned)m.z;
  return __uint_as_float((H & 1) ? (u & 0xffff0000u) : (u << 16));
}

// ---- histogram + degree sums ----
__global__ __launch_bounds__(256) void k_hist(const int* __restrict__ row,
                                              const int* __restrict__ col,
                                              const float* __restrict__ val,
                                              int* __restrict__ ecnt, int* __restrict__ ncnt,
                                              float* __restrict__ colsum, float* __restrict__ ddeg){
  int i = blockIdx.x*256 + threadIdx.x;
  if (i >= NNZ_) return;
  int c = col[i], r = row[i];
  atomicAdd(&ecnt[c], 1);
  atomicAdd(&ncnt[r], 1);
  atomicAdd(&colsum[c], val[i]);
  atomicAdd(&ddeg[r], val[c]);   // reference: adj_val[adj_col[i]]
}

// ---- fused hierarchical scan over BOTH count arrays ----
__device__ __forceinline__ void scanA_body(const int* cnt, int* ptr, int* bsum,
                                           int n, int blk){
  __shared__ int wsums[16];
  int idx = blk*1024 + threadIdx.x;
  int lane = threadIdx.x & 63, wid = threadIdx.x >> 6;
  int v = (idx < n) ? cnt[idx] : 0;
  int s = v;
#pragma unroll
  for (int off = 1; off < 64; off <<= 1){
    int t = __shfl_up(s, off);
    if (lane >= off) s += t;
  }
  if (lane == 63) wsums[wid] = s;
  __syncthreads();
  if (wid == 0 && lane < 16){
    int ws = wsums[lane];
    int t = ws;
#pragma unroll
    for (int off = 1; off < 16; off <<= 1){
      int u = __shfl_up(t, off);
      if (lane >= off) t += u;
    }
    wsums[lane] = t - ws;
  }
  __syncthreads();
  if (idx < n) ptr[idx] = wsums[wid] + s - v;
  if (threadIdx.x == 1023) bsum[blk] = wsums[15] + s;
}

__global__ __launch_bounds__(1024) void k_scanA2(const int* __restrict__ ecnt,
                                                 int* __restrict__ colptr,
                                                 int* __restrict__ bsumE, int nbE,
                                                 const int* __restrict__ ncnt,
                                                 int* __restrict__ rowptr,
                                                 int* __restrict__ bsumN){
  int b = blockIdx.x;
  if (b < nbE) scanA_body(ecnt, colptr, bsumE, N_EDGES, b);
  else         scanA_body(ncnt, rowptr, bsumN, N_NODES, b - nbE);
}

__device__ __forceinline__ void scanB_body(int* bsum, int nb, int* ptr, int n){
  __shared__ int sh[256];
  int t = threadIdx.x;
  int v = (t < nb) ? bsum[t] : 0;
  sh[t] = v;
  __syncthreads();
  for (int off = 1; off < 256; off <<= 1){
    int u = (t >= off) ? sh[t-off] : 0;
    __syncthreads();
    sh[t] += u;
    __syncthreads();
  }
  if (t < nb) bsum[t] = sh[t] - v;
  if (t == nb-1) ptr[n] = sh[t];
}

__global__ __launch_bounds__(256) void k_scanB2(int* __restrict__ bsumE, int nbE,
                                                int* __restrict__ colptr,
                                                int* __restrict__ bsumN, int nbN,
                                                int* __restrict__ rowptr){
  if (blockIdx.x == 0) scanB_body(bsumE, nbE, colptr, N_EDGES);
  else                 scanB_body(bsumN, nbN, rowptr, N_NODES);
}

__global__ __launch_bounds__(1024) void k_scanC2(int* __restrict__ colptr,
                                                 const int* __restrict__ bsumE, int nbE,
                                                 int* __restrict__ rowptr,
                                                 const int* __restrict__ bsumN){
  int b = blockIdx.x;
  if (b < nbE){
    int idx = b*1024 + threadIdx.x;
    if (idx < N_EDGES) colptr[idx] += bsumE[b];
  } else {
    int idx = (b - nbE)*1024 + threadIdx.x;
    if (idx < N_NODES) rowptr[idx] += bsumN[b - nbE];
  }
}

// ---- scatter: ONE packed int4 {row, val, rpos, 0} per nnz in col-CSR order ----
__global__ __launch_bounds__(256) void k_scatter(const int* __restrict__ row,
                                                 const int* __restrict__ col,
                                                 const float* __restrict__ val,
                                                 const int* __restrict__ colptr,
                                                 const int* __restrict__ rowptr,
                                                 int* __restrict__ ecur, int* __restrict__ ncur,
                                                 int4* __restrict__ rvp){
  int i = blockIdx.x*256 + threadIdx.x;
  if (i >= NNZ_) return;
  int c = col[i], r = row[i];
  int p = atomicAdd(&ecur[c], 1);
  int q = atomicAdd(&ncur[r], 1);
  rvp[colptr[c] + p] = make_int4(r, __float_as_int(val[i]), rowptr[r] + q, 0);
}

// ---- folded attention vectors ----
__global__ __launch_bounds__(256) void k_watt(const float* __restrict__ lin_w,
                                              const float* __restrict__ att,
                                              float* __restrict__ wattx,
                                              float* __restrict__ watte){
  int j = threadIdx.x;           // j = h*64 + k
  int h = j >> 6;
  float sx = 0.f, se = 0.f;
#pragma unroll
  for (int d = 0; d < DIM; ++d){
    float w = lin_w[(h*DIM + d)*DIM + (j & 63)];
    sx = fmaf(att[h*2*DIM + d],       w, sx);
    se = fmaf(att[h*2*DIM + DIM + d], w, se);
  }
  wattx[j] = sx;
  watte[j] = se;
}

// ---- folded FFN: Wf = w2@w1, bp = w2@b1 + b2 ----
__global__ __launch_bounds__(256) void k_wfold(const float* __restrict__ w1,
                                               const float* __restrict__ w2,
                                               const float* __restrict__ b1,
                                               const float* __restrict__ b2,
                                               float* __restrict__ Wf,
                                               float* __restrict__ bp){
  int tid = threadIdx.x;
#pragma unroll
  for (int m = 0; m < 16; ++m){
    int idx = m*256 + tid;
    int o = idx >> 6, k = idx & 63;
    float s = 0.f;
#pragma unroll
    for (int i = 0; i < 64; ++i)
      s = fmaf(w2[o*64 + i], w1[i*64 + k], s);
    Wf[idx] = s;
  }
  if (tid < 64){
    float s = b2[tid];
#pragma unroll
    for (int i = 0; i < 64; ++i)
      s = fmaf(w2[tid*64 + i], b1[i], s);
    bp[tid] = s;
  }
}

// ---- per-node projections + bf16 copy of x ----
__global__ __launch_bounds__(128) void k_pre(const float* __restrict__ x,
                                             const float* __restrict__ wattx,
                                             const float* __restrict__ watte,
                                             float4* __restrict__ snpe,
                                             unsigned short* __restrict__ xb){
  int lane = threadIdx.x & 63, wid = threadIdx.x >> 6;
  int n = blockIdx.x*2 + wid;
  if (n >= N_NODES) return;
  float xv = x[(size_t)n*DIM + lane];
  xb[(size_t)n*DIM + lane] = bf16of(xv);
  float s0 = wsum64(xv*wattx[lane]);
  float s1 = wsum64(xv*wattx[64+lane]);
  float s2 = wsum64(xv*wattx[128+lane]);
  float s3 = wsum64(xv*wattx[192+lane]);
  float p0 = wsum64(xv*watte[lane]);
  float p1 = wsum64(xv*watte[64+lane]);
  float p2 = wsum64(xv*watte[128+lane]);
  float p3 = wsum64(xv*watte[192+lane]);
  if (lane == 0){
    snpe[2*(size_t)n    ] = make_float4(s0,s1,s2,s3);
    snpe[2*(size_t)n + 1] = make_float4(p0,p1,p2,p3);
  }
}

// ---- merged: per-edge softmax + msg1 gather (bf16 x, packed meta, bf16 agg) ----
__global__ __launch_bounds__(128) void k_softagg(const int* __restrict__ colptr,
                                                 const int4* __restrict__ rvp,
                                                 const float4* __restrict__ snpe,
                                                 const float* __restrict__ colsum,
                                                 const unsigned short* __restrict__ xb,
                                                 float4* __restrict__ alphaC,
                                                 int4* __restrict__ cealpha,
                                                 unsigned short* __restrict__ aggB){
  __shared__ float4 aSh[128];
  int lane = threadIdx.x & 63, wid = threadIdx.x >> 6;
  int e = blockIdx.x*2 + wid;
  if (e >= N_EDGES) return;
  int sb = __builtin_amdgcn_readfirstlane(colptr[e]);
  int cnt = __builtin_amdgcn_readfirstlane(colptr[e+1]) - sb;
  if (cnt == 0) return;
  float rcs = 1.0f / colsum[e];
  float acc0=0,acc1=0,acc2=0,acc3=0;

  if (cnt <= 64){
    bool act = lane < cnt;
    int r = 0, rp = 0; float v = 0.f;
    float4 snv = make_float4(0,0,0,0), p = make_float4(0,0,0,0);
    if (act){
      int4 m = rvp[sb+lane];
      r = m.x; v = __int_as_float(m.y); rp = m.z;
      snv = snpe[2*(size_t)r];
      p   = snpe[2*(size_t)r + 1];
    }
    float se0 = wsum64(v*p.x)*rcs, se1 = wsum64(v*p.y)*rcs,
          se2 = wsum64(v*p.z)*rcs, se3 = wsum64(v*p.w)*rcs;
    float t0 = act ? lrelu2(snv.x+se0) : -1e30f;
    float t1 = act ? lrelu2(snv.y+se1) : -1e30f;
    float t2 = act ? lrelu2(snv.z+se2) : -1e30f;
    float t3 = act ? lrelu2(snv.w+se3) : -1e30f;
    float m0 = wmax64(t0), m1 = wmax64(t1), m2 = wmax64(t2), m3 = wmax64(t3);
    float e0 = act ? __expf(t0-m0) : 0.f;
    float e1 = act ? __expf(t1-m1) : 0.f;
    float e2 = act ? __expf(t2-m2) : 0.f;
    float e3 = act ? __expf(t3-m3) : 0.f;
    float q0 = wsum64(e0), q1 = wsum64(e1), q2 = wsum64(e2), q3 = wsum64(e3);
    float4 a = make_float4(e0/q0, e1/q1, e2/q2, e3/q3);   // inactive lanes -> 0
    if (act)
      cealpha[rp] = make_int4(e, (int)bfpack(a.x,a.y), (int)bfpack(a.z,a.w), 0);
    aSh[wid*64 + lane] = a;      // stage for uniform re-read (same wave)

    // gather: scalar meta + uniform LDS alpha + bf16 x loads, 4-deep
    int k = 0;
    for (; k + 4 <= cnt; k += 4){
      int r0 = rvp[sb+k].x, r1 = rvp[sb+k+1].x, r2 = rvp[sb+k+2].x, r3 = rvp[sb+k+3].x;
      float4 a0 = aSh[wid*64+k], a1 = aSh[wid*64+k+1],
             a2 = aSh[wid*64+k+2], a3 = aSh[wid*64+k+3];
      float x0 = bfup(xb[(size_t)r0*DIM + lane]);
      float x1 = bfup(xb[(size_t)r1*DIM + lane]);
      float x2 = bfup(xb[(size_t)r2*DIM + lane]);
      float x3 = bfup(xb[(size_t)r3*DIM + lane]);
      acc0 = fmaf(a0.x, x0, acc0); acc1 = fmaf(a0.y, x0, acc1);
      acc2 = fmaf(a0.z, x0, acc2); acc3 = fmaf(a0.w, x0, acc3);
      acc0 = fmaf(a1.x, x1, acc0); acc1 = fmaf(a1.y, x1, acc1);
      acc2 = fmaf(a1.z, x1, acc2); acc3 = fmaf(a1.w, x1, acc3);
      acc0 = fmaf(a2.x, x2, acc0); acc1 = fmaf(a2.y, x2, acc1);
      acc2 = fmaf(a2.z, x2, acc2); acc3 = fmaf(a2.w, x2, acc3);
      acc0 = fmaf(a3.x, x3, acc0); acc1 = fmaf(a3.y, x3, acc1);
      acc2 = fmaf(a3.z, x3, acc2); acc3 = fmaf(a3.w, x3, acc3);
    }
    for (; k < cnt; ++k){
      int r0 = rvp[sb+k].x;
      float4 a0 = aSh[wid*64+k];
      float x0 = bfup(xb[(size_t)r0*DIM + lane]);
      acc0 = fmaf(a0.x, x0, acc0); acc1 = fmaf(a0.y, x0, acc1);
      acc2 = fmaf(a0.z, x0, acc2); acc3 = fmaf(a0.w, x0, acc3);
    }
  } else {
    // ---- rare slow path (cnt > 64): multi-pass via alphaC scratch ----
    int s = sb;
    float a0=0,a1=0,a2=0,a3=0;
    for (int base = 0; base < cnt; base += 64){
      int j = s + base + lane;
      if (base + lane < cnt){
        int4 m = rvp[j];
        float v = __int_as_float(m.y);
        float4 p = snpe[2*(size_t)m.x + 1];
        a0 = fmaf(v,p.x,a0); a1 = fmaf(v,p.y,a1); a2 = fmaf(v,p.z,a2); a3 = fmaf(v,p.w,a3);
      }
    }
    float se0 = wsum64(a0)*rcs, se1 = wsum64(a1)*rcs, se2 = wsum64(a2)*rcs, se3 = wsum64(a3)*rcs;
    float m0=-1e30f,m1=-1e30f,m2=-1e30f,m3=-1e30f;
    for (int base = 0; base < cnt; base += 64){
      int j = s + base + lane;
      if (base + lane < cnt){
        float4 snv = snpe[2*(size_t)rvp[j].x];
        m0 = fmaxf(m0, lrelu2(snv.x+se0)); m1 = fmaxf(m1, lrelu2(snv.y+se1));
        m2 = fmaxf(m2, lrelu2(snv.z+se2)); m3 = fmaxf(m3, lrelu2(snv.w+se3));
      }
    }
    m0 = wmax64(m0); m1 = wmax64(m1); m2 = wmax64(m2); m3 = wmax64(m3);
    float q0=0,q1=0,q2=0,q3=0;
    for (int base = 0; base < cnt; base += 64){
      int j = s + base + lane;
      if (base + lane < cnt){
        float4 snv = snpe[2*(size_t)rvp[j].x];
        float e0 = __expf(lrelu2(snv.x+se0)-m0), e1 = __expf(lrelu2(snv.y+se1)-m1);
        float e2 = __expf(lrelu2(snv.z+se2)-m2), e3 = __expf(lrelu2(snv.w+se3)-m3);
        q0+=e0; q1+=e1; q2+=e2; q3+=e3;
        alphaC[j] = make_float4(e0,e1,e2,e3);
      }
    }
    q0 = wsum64(q0); q1 = wsum64(q1); q2 = wsum64(q2); q3 = wsum64(q3);
    float r0 = 1.f/q0, r1 = 1.f/q1, r2 = 1.f/q2, r3 = 1.f/q3;
    for (int base = 0; base < cnt; base += 64){
      int j = s + base + lane;
      if (base + lane < cnt){
        float4 av = alphaC[j];
        av = make_float4(av.x*r0, av.y*r1, av.z*r2, av.w*r3);
        alphaC[j] = av;
        cealpha[rvp[j].z] = make_int4(e, (int)bfpack(av.x,av.y), (int)bfpack(av.z,av.w), 0);
      }
    }
    for (int k = 0; k < cnt; ++k){
      int rj = rvp[sb+k].x;          // scalar load
      float4 al = alphaC[sb+k];      // scalar load
      float xv = bfup(xb[(size_t)rj*DIM + lane]);
      acc0 = fmaf(al.x, xv, acc0); acc1 = fmaf(al.y, xv, acc1);
      acc2 = fmaf(al.z, xv, acc2); acc3 = fmaf(al.w, xv, acc3);
    }
  }

  float binv = 1.0f/(float)cnt;
  size_t b = (size_t)e*256;
  aggB[b       + lane] = bf16of(acc0*binv);
  aggB[b +  64 + lane] = bf16of(acc1*binv);
  aggB[b + 128 + lane] = bf16of(acc2*binv);
  aggB[b + 192 + lane] = bf16of(acc3*binv);
}

// ---- per-edge lin_w transform (bf16 in) -> 4 HEAD PLANES eoP[h][e][d] (bf16) ----
// Plane layout means NO LDS transpose: wave h writes its 128B row directly.
__global__ __launch_bounds__(256) void k_eoT(const unsigned short* __restrict__ aggB,
                                             const float* __restrict__ lin_w,
                                             unsigned short* __restrict__ eoP){
  int lane = threadIdx.x & 63, h = threadIdx.x >> 6;
  float w[64];
  const float4* wr = (const float4*)(lin_w + ((size_t)h*64 + lane)*64);
#pragma unroll
  for (int k = 0; k < 16; ++k){
    float4 t = wr[k];
    w[4*k] = t.x; w[4*k+1] = t.y; w[4*k+2] = t.z; w[4*k+3] = t.w;
  }
  unsigned short* plane = eoP + (size_t)h*N_EDGES*64;
  int e0 = blockIdx.x*16;
#pragma unroll
  for (int el = 0; el < 16; el += 4){
    float av0 = bfup(aggB[(size_t)(e0+el  )*256 + h*64 + lane]);
    float av1 = bfup(aggB[(size_t)(e0+el+1)*256 + h*64 + lane]);
    float av2 = bfup(aggB[(size_t)(e0+el+2)*256 + h*64 + lane]);
    float av3 = bfup(aggB[(size_t)(e0+el+3)*256 + h*64 + lane]);
    float o0=0.f, o1=0.f, o2=0.f, o3=0.f;
#pragma unroll
    for (int k = 0; k < 64; ++k){
      float wk = w[k];
      o0 = fmaf(__shfl(av0, k), wk, o0);
      o1 = fmaf(__shfl(av1, k), wk, o1);
      o2 = fmaf(__shfl(av2, k), wk, o2);
      o3 = fmaf(__shfl(av3, k), wk, o3);
    }
    plane[(size_t)(e0+el  )*64 + lane] = bf16of(o0);
    plane[(size_t)(e0+el+1)*64 + lane] = bf16of(o1);
    plane[(size_t)(e0+el+2)*64 + lane] = bf16of(o2);
    plane[(size_t)(e0+el+3)*64 + lane] = bf16of(o3);
  }
}

// ---- per-sweep gather: plane H of eoP, alpha H from packed metadata ----
#define SEGH(J, KB, KE, H, PL) do { \
    int k = (KB); \
    for (; k + 4 <= (KE); k += 4){ \
      int4 m0 = cealpha[k], m1 = cealpha[k+1], m2 = cealpha[k+2], m3 = cealpha[k+3]; \
      float b0 = alphaOf(m0, H), b1 = alphaOf(m1, H), \
            b2 = alphaOf(m2, H), b3 = alphaOf(m3, H); \
      float v0 = bfup((PL)[(size_t)m0.x*64 + lane]); \
      float v1 = bfup((PL)[(size_t)m1.x*64 + lane]); \
      float v2 = bfup((PL)[(size_t)m2.x*64 + lane]); \
      float v3 = bfup((PL)[(size_t)m3.x*64 + lane]); \
      acc[J][H] = fmaf(v0, b0, acc[J][H]); \
      acc[J][H] = fmaf(v1, b1, acc[J][H]); \
      acc[J][H] = fmaf(v2, b2, acc[J][H]); \
      acc[J][H] = fmaf(v3, b3, acc[J][H]); \
    } \
    for (; k < (KE); ++k){ \
      int4 m0 = cealpha[k]; \
      float b0 = alphaOf(m0, H); \
      float v0 = bfup((PL)[(size_t)m0.x*64 + lane]); \
      acc[J][H] = fmaf(v0, b0, acc[J][H]); \
    } \
  } while(0)

// ---- fused: msg2 head-plane-sweep gather + LN1 + folded FFN + LN2 ----
__global__ __launch_bounds__(128) void k_final2(const float* __restrict__ x,
                                                const int* __restrict__ rowptr,
                                                const int4* __restrict__ cealpha,
                                                const unsigned short* __restrict__ eoP,
                                                const float* __restrict__ ddeg,
                                                const float* __restrict__ bias,
                                                const float* __restrict__ g1,
                                                const float* __restrict__ b1g,
                                                const float* __restrict__ g2,
                                                const float* __restrict__ b2g,
                                                const float* __restrict__ Wf,
                                                const float* __restrict__ bp,
                                                float* __restrict__ out){
  int lane = threadIdx.x & 63, wid = threadIdx.x >> 6;
  int nbase = blockIdx.x*8 + wid*4;
  int q0 = __builtin_amdgcn_readfirstlane(rowptr[nbase]);
  int q1 = __builtin_amdgcn_readfirstlane(rowptr[nbase+1]);
  int q2 = __builtin_amdgcn_readfirstlane(rowptr[nbase+2]);
  int q3 = __builtin_amdgcn_readfirstlane(rowptr[nbase+3]);
  int q4 = __builtin_amdgcn_readfirstlane(rowptr[nbase+4]);

  // early independent loads (overlap with gather issue)
  float xv[4];
#pragma unroll
  for (int j = 0; j < 4; ++j) xv[j] = x[(size_t)(nbase+j)*DIM + lane];
  float dd0 = ddeg[nbase], dd1 = ddeg[nbase+1], dd2 = ddeg[nbase+2], dd3 = ddeg[nbase+3];

  float acc[4][4];
#pragma unroll
  for (int j = 0; j < 4; ++j)
#pragma unroll
    for (int h = 0; h < 4; ++h) acc[j][h] = 0.f;

  // 4 head-plane sweeps: per sweep the active gather table is 2.56 MB (L2-fit)
#pragma unroll
  for (int H = 0; H < 4; ++H){
    const unsigned short* pl = eoP + (size_t)H*N_EDGES*64;
    SEGH(0, q0, q1, H, pl);
    SEGH(1, q1, q2, H, pl);
    SEGH(2, q2, q3, H, pl);
    SEGH(3, q3, q4, H, pl);
  }

  // FFN weights + LN params (loaded after gather)
  float w[64];
  const float4* wr = (const float4*)(Wf + (size_t)lane*64);
#pragma unroll
  for (int k = 0; k < 16; ++k){
    float4 t = wr[k];
    w[4*k] = t.x; w[4*k+1] = t.y; w[4*k+2] = t.z; w[4*k+3] = t.w;
  }
  float biasv = bias[lane], bpv = bp[lane];
  float g1v = g1[lane], b1gv = b1g[lane], g2v = g2[lane], b2gv = b2g[lane];

  // LN1 per node
  float ddv[4] = {dd0, dd1, dd2, dd3};
  float hs[4];
#pragma unroll
  for (int j = 0; j < 4; ++j){
    float dd = ddv[j];
    float dinv = dd > 0.f ? 0.25f/dd : 0.f;
    float conv = (acc[j][0]+acc[j][1]+acc[j][2]+acc[j][3])*dinv;
    float t = xv[j] + conv + biasv;
    float mu = wsum64(t) * (1.f/64.f);
    float dv = t - mu;
    float var = wsum64(dv*dv) * (1.f/64.f);
    hs[j] = dv * rsqrtf(var + LNEPS) * g1v + b1gv;
  }

  // folded FFN: 4 independent chains
  float a0 = bpv, a1 = bpv, a2 = bpv, a3 = bpv;
#pragma unroll
  for (int k = 0; k < 64; ++k){
    a0 = fmaf(__shfl(hs[0], k), w[k], a0);
    a1 = fmaf(__shfl(hs[1], k), w[k], a1);
    a2 = fmaf(__shfl(hs[2], k), w[k], a2);
    a3 = fmaf(__shfl(hs[3], k), w[k], a3);
  }

  float fa[4] = {a0, a1, a2, a3};
#pragma unroll
  for (int j = 0; j < 4; ++j){
    int n = nbase + j;
    float ffn = fa[j] > 0.f ? fa[j] : 0.01f*fa[j];
    float t2 = hs[j] + ffn;
    float mu2 = wsum64(t2) * (1.f/64.f);
    float dv2 = t2 - mu2;
    float var2 = wsum64(dv2*dv2) * (1.f/64.f);
    out[(size_t)n*DIM + lane] = dv2 * rsqrtf(var2 + LNEPS) * g2v + b2gv;
  }
}

extern "C" void kernel_launch(void* const* d_in, const int* in_sizes, int n_in,
                              void* d_out, int out_size, void* d_ws, size_t ws_size,
                              hipStream_t stream){
  const float* x     = (const float*)d_in[0];
  const int*   row   = (const int*)d_in[1];
  const int*   col   = (const int*)d_in[2];
  const float* val   = (const float*)d_in[3];
  const float* lin_w = (const float*)d_in[5];
  const float* att   = (const float*)d_in[6];
  const float* bias  = (const float*)d_in[7];
  const float* g1    = (const float*)d_in[8];
  const float* b1g   = (const float*)d_in[9];
  const float* g2    = (const float*)d_in[10];
  const float* b2g   = (const float*)d_in[11];
  const float* w1    = (const float*)d_in[12];
  const float* b1    = (const float*)d_in[13];
  const float* w2    = (const float*)d_in[14];
  const float* b2    = (const float*)d_in[15];
  float* out = (float*)d_out;
  float* ws  = (float*)d_ws;

  constexpr size_t E = N_EDGES, Nn = N_NODES;
  constexpr size_t o_ecnt   = 0;                   // E ints (zeroed)
  constexpr size_t o_ncnt   = o_ecnt + E;          // N ints
  constexpr size_t o_ecur   = o_ncnt + Nn;         // E ints
  constexpr size_t o_ncur   = o_ecur + E;          // N ints
  constexpr size_t o_colsum = o_ncur + Nn;         // E f
  constexpr size_t o_ddeg   = o_colsum + E;        // N f
  constexpr size_t ZEND     = o_ddeg + Nn;
  constexpr size_t o_colptr = ZEND;                // E+4 ints
  constexpr size_t o_rowptr = o_colptr + E + 4;    // N+4 ints
  constexpr size_t o_bsumE  = o_rowptr + Nn + 4;   // 256 ints
  constexpr size_t o_bsumN  = o_bsumE + 256;       // 256 ints
  constexpr size_t o_rvp    = (o_bsumN + 256 + 3) & ~(size_t)3;  // NNZ int4
  constexpr size_t o_wattx  = o_rvp + 4*(size_t)NNZ_;  // 256 f
  constexpr size_t o_watte  = o_wattx + 256;       // 256 f
  constexpr size_t o_Wf     = o_watte + 256;       // 4096 f
  constexpr size_t o_bp     = o_Wf + 4096;         // 64 f
  constexpr size_t o_snpe   = o_bp + 64;           // 8N f
  constexpr size_t o_alphaC = o_snpe + 8*Nn;       // 4*NNZ f (slow-path scratch)
  constexpr size_t o_ceal   = o_alphaC + 4*(size_t)NNZ_; // NNZ int4
  constexpr size_t o_xb     = o_ceal + 4*(size_t)NNZ_;   // N*64 ushort = 32N f
  constexpr size_t o_aggB   = o_xb + 32*Nn;        // E*256 ushort = 128E f
  constexpr size_t o_eo     = o_aggB + 128*E;      // 4 planes × E*64 ushort

  int*    ecnt   = (int*)(ws + o_ecnt);
  int*    ncnt   = (int*)(ws + o_ncnt);
  int*    ecur   = (int*)(ws + o_ecur);
  int*    ncur   = (int*)(ws + o_ncur);
  float*  colsum = ws + o_colsum;
  float*  ddeg   = ws + o_ddeg;
  int*    colptr = (int*)(ws + o_colptr);
  int*    rowptr = (int*)(ws + o_rowptr);
  int*    bsumE  = (int*)(ws + o_bsumE);
  int*    bsumN  = (int*)(ws + o_bsumN);
  int4*   rvp    = (int4*)(ws + o_rvp);
  float*  wattx  = ws + o_wattx;
  float*  watte  = ws + o_watte;
  float*  Wf     = ws + o_Wf;
  float*  bp     = ws + o_bp;
  float4* snpe   = (float4*)(ws + o_snpe);
  float4* alphaC = (float4*)(ws + o_alphaC);
  int4*   cealpha= (int4*)(ws + o_ceal);
  unsigned short* xb   = (unsigned short*)(ws + o_xb);
  unsigned short* aggB = (unsigned short*)(ws + o_aggB);
  unsigned short* eoP  = (unsigned short*)(ws + o_eo);

  hipMemsetAsync(ws, 0, ZEND*sizeof(float), stream);

  k_hist<<<(NNZ_+255)/256, 256, 0, stream>>>(row, col, val, ecnt, ncnt, colsum, ddeg);

  int nbE = (int)((E + 1023)/1024);   // 20
  int nbN = (int)((Nn + 1023)/1024);  // 98
  k_scanA2<<<nbE + nbN, 1024, 0, stream>>>(ecnt, colptr, bsumE, nbE, ncnt, rowptr, bsumN);
  k_scanB2<<<2, 256, 0, stream>>>(bsumE, nbE, colptr, bsumN, nbN, rowptr);
  k_scanC2<<<nbE + nbN, 1024, 0, stream>>>(colptr, bsumE, nbE, rowptr, bsumN);

  k_scatter<<<(NNZ_+255)/256, 256, 0, stream>>>(row, col, val, colptr, rowptr,
                                                ecur, ncur, rvp);

  k_watt<<<1, 256, 0, stream>>>(lin_w, att, wattx, watte);
  k_wfold<<<1, 256, 0, stream>>>(w1, w2, b1, b2, Wf, bp);
  k_pre<<<(int)((Nn+1)/2), 128, 0, stream>>>(x, wattx, watte, snpe, xb);
  k_softagg<<<(int)((E+1)/2), 128, 0, stream>>>(colptr, rvp, snpe, colsum, xb,
                                                alphaC, cealpha, aggB);
  k_eoT<<<(int)(E/16), 256, 0, stream>>>(aggB, lin_w, eoP);
  k_final2<<<(int)(Nn/8), 128, 0, stream>>>(x, rowptr, cealpha, eoP, ddeg,
                                            bias, g1, b1g, g2, b2g, Wf, bp, out);
}

// Round 14
// 442.665 us; speedup vs baseline: 1.0292x; 1.0292x over previous
//
#include <hip/hip_runtime.h>

#define N_NODES 100000
#define N_EDGES 20000
#define DIM 64
#define HEADS 4
#define NNZ_ 500000
#define LNEPS 1e-5f

__device__ __forceinline__ float wsum64(float v){
#pragma unroll
  for (int off = 32; off; off >>= 1) v += __shfl_xor(v, off);
  return v;
}
__device__ __forceinline__ float wmax64(float v){
#pragma unroll
  for (int off = 32; off; off >>= 1) v = fmaxf(v, __shfl_xor(v, off));
  return v;
}
__device__ __forceinline__ float lrelu2(float a){ return a > 0.f ? a : 0.2f*a; }

// pack 2 floats -> 2 bf16 (RNE) in one uint (a in low16, b in high16)
__device__ __forceinline__ unsigned bfpack(float a, float b){
  unsigned ua = __float_as_uint(a), ub = __float_as_uint(b);
  ua += 0x7fffu + ((ua >> 16) & 1u);
  ub += 0x7fffu + ((ub >> 16) & 1u);
  return (ua >> 16) | (ub & 0xffff0000u);
}
__device__ __forceinline__ unsigned short bf16of(float f){
  unsigned u = __float_as_uint(f);
  u += 0x7fffu + ((u >> 16) & 1u);
  return (unsigned short)(u >> 16);
}
__device__ __forceinline__ float bfup(unsigned short s){
  return __uint_as_float(((unsigned)s) << 16);
}

// ---- manual fp8 e4m3 (RNE, flush<2^-6, clamp at 448) ----
__device__ __forceinline__ unsigned fp8of(float f){
  unsigned u = __float_as_uint(f);
  unsigned s = (u >> 24) & 0x80u;
  unsigned au = u & 0x7fffffffu;
  if (au < 0x3c800000u) return s;            // |f| < 2^-6 -> signed zero
  au += 0x7ffffu + ((au >> 20) & 1u);        // RNE to 3 mantissa bits
  unsigned e = (au >> 23) - 120u;            // rebias 127->7
  unsigned m = (au >> 20) & 7u;
  if (e > 15u){ e = 15u; m = 6u; }           // clamp (avoid NaN encoding)
  return s | (e << 3) | m;
}
__device__ __forceinline__ float fp8up(unsigned b){
  unsigned s = (b & 0x80u) << 24;
  unsigned e = (b >> 3) & 0xFu;
  unsigned m = b & 7u;
  if (e == 0u) return __uint_as_float(s);    // we never encode denormals
  return __uint_as_float(s | ((e + 120u) << 23) | (m << 20));
}

// ---- histogram + degree sums ----
__global__ __launch_bounds__(256) void k_hist(const int* __restrict__ row,
                                              const int* __restrict__ col,
                                              const float* __restrict__ val,
                                              int* __restrict__ ecnt, int* __restrict__ ncnt,
                                              float* __restrict__ colsum, float* __restrict__ ddeg){
  int i = blockIdx.x*256 + threadIdx.x;
  if (i >= NNZ_) return;
  int c = col[i], r = row[i];
  atomicAdd(&ecnt[c], 1);
  atomicAdd(&ncnt[r], 1);
  atomicAdd(&colsum[c], val[i]);
  atomicAdd(&ddeg[r], val[c]);   // reference: adj_val[adj_col[i]]
}

// ---- fused hierarchical scan over BOTH count arrays ----
__device__ __forceinline__ void scanA_body(const int* cnt, int* ptr, int* bsum,
                                           int n, int blk){
  __shared__ int wsums[16];
  int idx = blk*1024 + threadIdx.x;
  int lane = threadIdx.x & 63, wid = threadIdx.x >> 6;
  int v = (idx < n) ? cnt[idx] : 0;
  int s = v;
#pragma unroll
  for (int off = 1; off < 64; off <<= 1){
    int t = __shfl_up(s, off);
    if (lane >= off) s += t;
  }
  if (lane == 63) wsums[wid] = s;
  __syncthreads();
  if (wid == 0 && lane < 16){
    int ws = wsums[lane];
    int t = ws;
#pragma unroll
    for (int off = 1; off < 16; off <<= 1){
      int u = __shfl_up(t, off);
      if (lane >= off) t += u;
    }
    wsums[lane] = t - ws;
  }
  __syncthreads();
  if (idx < n) ptr[idx] = wsums[wid] + s - v;
  if (threadIdx.x == 1023) bsum[blk] = wsums[15] + s;
}

__global__ __launch_bounds__(1024) void k_scanA2(const int* __restrict__ ecnt,
                                                 int* __restrict__ colptr,
                                                 int* __restrict__ bsumE, int nbE,
                                                 const int* __restrict__ ncnt,
                                                 int* __restrict__ rowptr,
                                                 int* __restrict__ bsumN){
  int b = blockIdx.x;
  if (b < nbE) scanA_body(ecnt, colptr, bsumE, N_EDGES, b);
  else         scanA_body(ncnt, rowptr, bsumN, N_NODES, b - nbE);
}

__device__ __forceinline__ void scanB_body(int* bsum, int nb, int* ptr, int n){
  __shared__ int sh[256];
  int t = threadIdx.x;
  int v = (t < nb) ? bsum[t] : 0;
  sh[t] = v;
  __syncthreads();
  for (int off = 1; off < 256; off <<= 1){
    int u = (t >= off) ? sh[t-off] : 0;
    __syncthreads();
    sh[t] += u;
    __syncthreads();
  }
  if (t < nb) bsum[t] = sh[t] - v;
  if (t == nb-1) ptr[n] = sh[t];
}

__global__ __launch_bounds__(256) void k_scanB2(int* __restrict__ bsumE, int nbE,
                                                int* __restrict__ colptr,
                                                int* __restrict__ bsumN, int nbN,
                                                int* __restrict__ rowptr){
  if (blockIdx.x == 0) scanB_body(bsumE, nbE, colptr, N_EDGES);
  else                 scanB_body(bsumN, nbN, rowptr, N_NODES);
}

__global__ __launch_bounds__(1024) void k_scanC2(int* __restrict__ colptr,
                                                 const int* __restrict__ bsumE, int nbE,
                                                 int* __restrict__ rowptr,
                                                 const int* __restrict__ bsumN){
  int b = blockIdx.x;
  if (b < nbE){
    int idx = b*1024 + threadIdx.x;
    if (idx < N_EDGES) colptr[idx] += bsumE[b];
  } else {
    int idx = (b - nbE)*1024 + threadIdx.x;
    if (idx < N_NODES) rowptr[idx] += bsumN[b - nbE];
  }
}

// ---- scatter: ONE packed int4 {row, val, rpos, 0} per nnz in col-CSR order ----
__global__ __launch_bounds__(256) void k_scatter(const int* __restrict__ row,
                                                 const int* __restrict__ col,
                                                 const float* __restrict__ val,
                                                 const int* __restrict__ colptr,
                                                 const int* __restrict__ rowptr,
                                                 int* __restrict__ ecur, int* __restrict__ ncur,
                                                 int4* __restrict__ rvp){
  int i = blockIdx.x*256 + threadIdx.x;
  if (i >= NNZ_) return;
  int c = col[i], r = row[i];
  int p = atomicAdd(&ecur[c], 1);
  int q = atomicAdd(&ncur[r], 1);
  rvp[colptr[c] + p] = make_int4(r, __float_as_int(val[i]), rowptr[r] + q, 0);
}

// ---- folded attention vectors ----
__global__ __launch_bounds__(256) void k_watt(const float* __restrict__ lin_w,
                                              const float* __restrict__ att,
                                              float* __restrict__ wattx,
                                              float* __restrict__ watte){
  int j = threadIdx.x;           // j = h*64 + k
  int h = j >> 6;
  float sx = 0.f, se = 0.f;
#pragma unroll
  for (int d = 0; d < DIM; ++d){
    float w = lin_w[(h*DIM + d)*DIM + (j & 63)];
    sx = fmaf(att[h*2*DIM + d],       w, sx);
    se = fmaf(att[h*2*DIM + DIM + d], w, se);
  }
  wattx[j] = sx;
  watte[j] = se;
}

// ---- folded FFN: Wf = w2@w1, bp = w2@b1 + b2 ----
__global__ __launch_bounds__(256) void k_wfold(const float* __restrict__ w1,
                                               const float* __restrict__ w2,
                                               const float* __restrict__ b1,
                                               const float* __restrict__ b2,
                                               float* __restrict__ Wf,
                                               float* __restrict__ bp){
  int tid = threadIdx.x;
#pragma unroll
  for (int m = 0; m < 16; ++m){
    int idx = m*256 + tid;
    int o = idx >> 6, k = idx & 63;
    float s = 0.f;
#pragma unroll
    for (int i = 0; i < 64; ++i)
      s = fmaf(w2[o*64 + i], w1[i*64 + k], s);
    Wf[idx] = s;
  }
  if (tid < 64){
    float s = b2[tid];
#pragma unroll
    for (int i = 0; i < 64; ++i)
      s = fmaf(w2[tid*64 + i], b1[i], s);
    bp[tid] = s;
  }
}

// ---- per-node projections + fp8 copy of x ----
__global__ __launch_bounds__(128) void k_pre(const float* __restrict__ x,
                                             const float* __restrict__ wattx,
                                             const float* __restrict__ watte,
                                             float4* __restrict__ snpe,
                                             unsigned char* __restrict__ xb){
  int lane = threadIdx.x & 63, wid = threadIdx.x >> 6;
  int n = blockIdx.x*2 + wid;
  if (n >= N_NODES) return;
  float xv = x[(size_t)n*DIM + lane];
  xb[(size_t)n*DIM + lane] = (unsigned char)fp8of(xv);
  float s0 = wsum64(xv*wattx[lane]);
  float s1 = wsum64(xv*wattx[64+lane]);
  float s2 = wsum64(xv*wattx[128+lane]);
  float s3 = wsum64(xv*wattx[192+lane]);
  float p0 = wsum64(xv*watte[lane]);
  float p1 = wsum64(xv*watte[64+lane]);
  float p2 = wsum64(xv*watte[128+lane]);
  float p3 = wsum64(xv*watte[192+lane]);
  if (lane == 0){
    snpe[2*(size_t)n    ] = make_float4(s0,s1,s2,s3);
    snpe[2*(size_t)n + 1] = make_float4(p0,p1,p2,p3);
  }
}

// ---- merged: per-edge softmax + msg1 gather (fp8 x, packed meta, bf16 agg) ----
__global__ __launch_bounds__(128) void k_softagg(const int* __restrict__ colptr,
                                                 const int4* __restrict__ rvp,
                                                 const float4* __restrict__ snpe,
                                                 const float* __restrict__ colsum,
                                                 const unsigned char* __restrict__ xb,
                                                 float4* __restrict__ alphaC,
                                                 int4* __restrict__ cealpha,
                                                 unsigned short* __restrict__ aggB){
  __shared__ float4 aSh[128];
  int lane = threadIdx.x & 63, wid = threadIdx.x >> 6;
  int e = blockIdx.x*2 + wid;
  if (e >= N_EDGES) return;
  int sb = __builtin_amdgcn_readfirstlane(colptr[e]);
  int cnt = __builtin_amdgcn_readfirstlane(colptr[e+1]) - sb;
  if (cnt == 0) return;
  float rcs = 1.0f / colsum[e];
  float acc0=0,acc1=0,acc2=0,acc3=0;

  if (cnt <= 64){
    bool act = lane < cnt;
    int r = 0, rp = 0; float v = 0.f;
    float4 snv = make_float4(0,0,0,0), p = make_float4(0,0,0,0);
    if (act){
      int4 m = rvp[sb+lane];
      r = m.x; v = __int_as_float(m.y); rp = m.z;
      snv = snpe[2*(size_t)r];
      p   = snpe[2*(size_t)r + 1];
    }
    float se0 = wsum64(v*p.x)*rcs, se1 = wsum64(v*p.y)*rcs,
          se2 = wsum64(v*p.z)*rcs, se3 = wsum64(v*p.w)*rcs;
    float t0 = act ? lrelu2(snv.x+se0) : -1e30f;
    float t1 = act ? lrelu2(snv.y+se1) : -1e30f;
    float t2 = act ? lrelu2(snv.z+se2) : -1e30f;
    float t3 = act ? lrelu2(snv.w+se3) : -1e30f;
    float m0 = wmax64(t0), m1 = wmax64(t1), m2 = wmax64(t2), m3 = wmax64(t3);
    float e0 = act ? __expf(t0-m0) : 0.f;
    float e1 = act ? __expf(t1-m1) : 0.f;
    float e2 = act ? __expf(t2-m2) : 0.f;
    float e3 = act ? __expf(t3-m3) : 0.f;
    float q0 = wsum64(e0), q1 = wsum64(e1), q2 = wsum64(e2), q3 = wsum64(e3);
    float4 a = make_float4(e0/q0, e1/q1, e2/q2, e3/q3);   // inactive lanes -> 0
    if (act)
      cealpha[rp] = make_int4(e, (int)bfpack(a.x,a.y), (int)bfpack(a.z,a.w), 0);
    aSh[wid*64 + lane] = a;      // stage for uniform re-read (same wave)

    // gather: scalar meta + uniform LDS alpha + fp8 x loads, 4-deep
    int k = 0;
    for (; k + 4 <= cnt; k += 4){
      int r0 = rvp[sb+k].x, r1 = rvp[sb+k+1].x, r2 = rvp[sb+k+2].x, r3 = rvp[sb+k+3].x;
      float4 a0 = aSh[wid*64+k], a1 = aSh[wid*64+k+1],
             a2 = aSh[wid*64+k+2], a3 = aSh[wid*64+k+3];
      float x0 = fp8up((unsigned)xb[(size_t)r0*DIM + lane]);
      float x1 = fp8up((unsigned)xb[(size_t)r1*DIM + lane]);
      float x2 = fp8up((unsigned)xb[(size_t)r2*DIM + lane]);
      float x3 = fp8up((unsigned)xb[(size_t)r3*DIM + lane]);
      acc0 = fmaf(a0.x, x0, acc0); acc1 = fmaf(a0.y, x0, acc1);
      acc2 = fmaf(a0.z, x0, acc2); acc3 = fmaf(a0.w, x0, acc3);
      acc0 = fmaf(a1.x, x1, acc0); acc1 = fmaf(a1.y, x1, acc1);
      acc2 = fmaf(a1.z, x1, acc2); acc3 = fmaf(a1.w, x1, acc3);
      acc0 = fmaf(a2.x, x2, acc0); acc1 = fmaf(a2.y, x2, acc1);
      acc2 = fmaf(a2.z, x2, acc2); acc3 = fmaf(a2.w, x2, acc3);
      acc0 = fmaf(a3.x, x3, acc0); acc1 = fmaf(a3.y, x3, acc1);
      acc2 = fmaf(a3.z, x3, acc2); acc3 = fmaf(a3.w, x3, acc3);
    }
    for (; k < cnt; ++k){
      int r0 = rvp[sb+k].x;
      float4 a0 = aSh[wid*64+k];
      float x0 = fp8up((unsigned)xb[(size_t)r0*DIM + lane]);
      acc0 = fmaf(a0.x, x0, acc0); acc1 = fmaf(a0.y, x0, acc1);
      acc2 = fmaf(a0.z, x0, acc2); acc3 = fmaf(a0.w, x0, acc3);
    }
  } else {
    // ---- rare slow path (cnt > 64): multi-pass via alphaC scratch ----
    int s = sb;
    float a0=0,a1=0,a2=0,a3=0;
    for (int base = 0; base < cnt; base += 64){
      int j = s + base + lane;
      if (base + lane < cnt){
        int4 m = rvp[j];
        float v = __int_as_float(m.y);
        float4 p = snpe[2*(size_t)m.x + 1];
        a0 = fmaf(v,p.x,a0); a1 = fmaf(v,p.y,a1); a2 = fmaf(v,p.z,a2); a3 = fmaf(v,p.w,a3);
      }
    }
    float se0 = wsum64(a0)*rcs, se1 = wsum64(a1)*rcs, se2 = wsum64(a2)*rcs, se3 = wsum64(a3)*rcs;
    float m0=-1e30f,m1=-1e30f,m2=-1e30f,m3=-1e30f;
    for (int base = 0; base < cnt; base += 64){
      int j = s + base + lane;
      if (base + lane < cnt){
        float4 snv = snpe[2*(size_t)rvp[j].x];
        m0 = fmaxf(m0, lrelu2(snv.x+se0)); m1 = fmaxf(m1, lrelu2(snv.y+se1));
        m2 = fmaxf(m2, lrelu2(snv.z+se2)); m3 = fmaxf(m3, lrelu2(snv.w+se3));
      }
    }
    m0 = wmax64(m0); m1 = wmax64(m1); m2 = wmax64(m2); m3 = wmax64(m3);
    float q0=0,q1=0,q2=0,q3=0;
    for (int base = 0; base < cnt; base += 64){
      int j = s + base + lane;
      if (base + lane < cnt){
        float4 snv = snpe[2*(size_t)rvp[j].x];
        float e0 = __expf(lrelu2(snv.x+se0)-m0), e1 = __expf(lrelu2(snv.y+se1)-m1);
        float e2 = __expf(lrelu2(snv.z+se2)-m2), e3 = __expf(lrelu2(snv.w+se3)-m3);
        q0+=e0; q1+=e1; q2+=e2; q3+=e3;
        alphaC[j] = make_float4(e0,e1,e2,e3);
      }
    }
    q0 = wsum64(q0); q1 = wsum64(q1); q2 = wsum64(q2); q3 = wsum64(q3);
    float r0 = 1.f/q0, r1 = 1.f/q1, r2 = 1.f/q2, r3 = 1.f/q3;
    for (int base = 0; base < cnt; base += 64){
      int j = s + base + lane;
      if (base + lane < cnt){
        float4 av = alphaC[j];
        av = make_float4(av.x*r0, av.y*r1, av.z*r2, av.w*r3);
        alphaC[j] = av;
        cealpha[rvp[j].z] = make_int4(e, (int)bfpack(av.x,av.y), (int)bfpack(av.z,av.w), 0);
      }
    }
    for (int k = 0; k < cnt; ++k){
      int rj = rvp[sb+k].x;          // scalar load
      float4 al = alphaC[sb+k];      // scalar load
      float xv = fp8up((unsigned)xb[(size_t)rj*DIM + lane]);
      acc0 = fmaf(al.x, xv, acc0); acc1 = fmaf(al.y, xv, acc1);
      acc2 = fmaf(al.z, xv, acc2); acc3 = fmaf(al.w, xv, acc3);
    }
  }

  float binv = 1.0f/(float)cnt;
  size_t b = (size_t)e*256;
  aggB[b       + lane] = bf16of(acc0*binv);
  aggB[b +  64 + lane] = bf16of(acc1*binv);
  aggB[b + 128 + lane] = bf16of(acc2*binv);
  aggB[b + 192 + lane] = bf16of(acc3*binv);
}

// ---- per-edge lin_w transform (bf16 in), head-interleaved FP8 out: eoT4[e][d]=uint(4 heads)
__global__ __launch_bounds__(256) void k_eoT(const unsigned short* __restrict__ aggB,
                                             const float* __restrict__ lin_w,
                                             unsigned* __restrict__ eoT4){
  __shared__ float L[16*260];
  int lane = threadIdx.x & 63, h = threadIdx.x >> 6;
  float w[64];
  const float4* wr = (const float4*)(lin_w + ((size_t)h*64 + lane)*64);
#pragma unroll
  for (int k = 0; k < 16; ++k){
    float4 t = wr[k];
    w[4*k] = t.x; w[4*k+1] = t.y; w[4*k+2] = t.z; w[4*k+3] = t.w;
  }
  int e0 = blockIdx.x*16;
#pragma unroll
  for (int el = 0; el < 16; el += 4){
    float av0 = bfup(aggB[(size_t)(e0+el  )*256 + h*64 + lane]);
    float av1 = bfup(aggB[(size_t)(e0+el+1)*256 + h*64 + lane]);
    float av2 = bfup(aggB[(size_t)(e0+el+2)*256 + h*64 + lane]);
    float av3 = bfup(aggB[(size_t)(e0+el+3)*256 + h*64 + lane]);
    float o0=0.f, o1=0.f, o2=0.f, o3=0.f;
#pragma unroll
    for (int k = 0; k < 64; ++k){
      float wk = w[k];
      o0 = fmaf(__shfl(av0, k), wk, o0);
      o1 = fmaf(__shfl(av1, k), wk, o1);
      o2 = fmaf(__shfl(av2, k), wk, o2);
      o3 = fmaf(__shfl(av3, k), wk, o3);
    }
    L[(el  )*260 + lane*4 + h] = o0;
    L[(el+1)*260 + lane*4 + h] = o1;
    L[(el+2)*260 + lane*4 + h] = o2;
    L[(el+3)*260 + lane*4 + h] = o3;
  }
  __syncthreads();
  int tid = threadIdx.x;
#pragma unroll
  for (int p = 0; p < 4; ++p){
    int el = p*4 + (tid >> 6);
    int l = tid & 63;
    const float* Lr = &L[el*260 + l*4];
    unsigned v = fp8of(Lr[0]) | (fp8of(Lr[1]) << 8) |
                 (fp8of(Lr[2]) << 16) | (fp8of(Lr[3]) << 24);
    eoT4[(size_t)(e0+el)*64 + l] = v;
  }
}

#define ACC4(J, V, M) { \
  float u0 = fp8up((V) & 0xffu); \
  float u1 = fp8up(((V) >> 8) & 0xffu); \
  float u2 = fp8up(((V) >> 16) & 0xffu); \
  float u3 = fp8up((V) >> 24); \
  float ax = __uint_as_float(((unsigned)(M).y) << 16); \
  float ay = __uint_as_float(((unsigned)(M).y) & 0xffff0000u); \
  float az = __uint_as_float(((unsigned)(M).z) << 16); \
  float aw = __uint_as_float(((unsigned)(M).z) & 0xffff0000u); \
  acc[J][0] = fmaf(u0, ax, acc[J][0]); \
  acc[J][1] = fmaf(u1, ay, acc[J][1]); \
  acc[J][2] = fmaf(u2, az, acc[J][2]); \
  acc[J][3] = fmaf(u3, aw, acc[J][3]); }

#define SEG(J, KB, KE) do { \
    int k = (KB); \
    for (; k + 4 <= (KE); k += 4){ \
      int4 m0 = cealpha[k], m1 = cealpha[k+1], m2 = cealpha[k+2], m3 = cealpha[k+3]; \
      unsigned v0 = eoT4[(size_t)m0.x*64 + lane]; \
      unsigned v1 = eoT4[(size_t)m1.x*64 + lane]; \
      unsigned v2 = eoT4[(size_t)m2.x*64 + lane]; \
      unsigned v3 = eoT4[(size_t)m3.x*64 + lane]; \
      ACC4(J, v0, m0); ACC4(J, v1, m1); ACC4(J, v2, m2); ACC4(J, v3, m3); \
    } \
    for (; k < (KE); ++k){ \
      int4 m0 = cealpha[k]; \
      unsigned v0 = eoT4[(size_t)m0.x*64 + lane]; \
      ACC4(J, v0, m0); \
    } \
  } while(0)

// ---- fused: msg2 gather (fp8 table, packed meta) + LN1 + folded FFN + LN2 ----
__global__ __launch_bounds__(128) void k_final2(const float* __restrict__ x,
                                                const int* __restrict__ rowptr,
                                                const int4* __restrict__ cealpha,
                                                const unsigned* __restrict__ eoT4,
                                                const float* __restrict__ ddeg,
                                                const float* __restrict__ bias,
                                                const float* __restrict__ g1,
                                                const float* __restrict__ b1g,
                                                const float* __restrict__ g2,
                                                const float* __restrict__ b2g,
                                                const float* __restrict__ Wf,
                                                const float* __restrict__ bp,
                                                float* __restrict__ out){
  int lane = threadIdx.x & 63, wid = threadIdx.x >> 6;
  int nbase = blockIdx.x*8 + wid*4;
  int q0 = __builtin_amdgcn_readfirstlane(rowptr[nbase]);
  int q1 = __builtin_amdgcn_readfirstlane(rowptr[nbase+1]);
  int q2 = __builtin_amdgcn_readfirstlane(rowptr[nbase+2]);
  int q3 = __builtin_amdgcn_readfirstlane(rowptr[nbase+3]);
  int q4 = __builtin_amdgcn_readfirstlane(rowptr[nbase+4]);

  // early independent loads (overlap with gather issue)
  float xv[4];
#pragma unroll
  for (int j = 0; j < 4; ++j) xv[j] = x[(size_t)(nbase+j)*DIM + lane];
  float dd0 = ddeg[nbase], dd1 = ddeg[nbase+1], dd2 = ddeg[nbase+2], dd3 = ddeg[nbase+3];

  float acc[4][4];
#pragma unroll
  for (int j = 0; j < 4; ++j)
#pragma unroll
    for (int h = 0; h < 4; ++h) acc[j][h] = 0.f;

  SEG(0, q0, q1);
  SEG(1, q1, q2);
  SEG(2, q2, q3);
  SEG(3, q3, q4);

  // FFN weights + LN params (loaded after gather)
  float w[64];
  const float4* wr = (const float4*)(Wf + (size_t)lane*64);
#pragma unroll
  for (int k = 0; k < 16; ++k){
    float4 t = wr[k];
    w[4*k] = t.x; w[4*k+1] = t.y; w[4*k+2] = t.z; w[4*k+3] = t.w;
  }
  float biasv = bias[lane], bpv = bp[lane];
  float g1v = g1[lane], b1gv = b1g[lane], g2v = g2[lane], b2gv = b2g[lane];

  // LN1 per node
  float ddv[4] = {dd0, dd1, dd2, dd3};
  float hs[4];
#pragma unroll
  for (int j = 0; j < 4; ++j){
    float dd = ddv[j];
    float dinv = dd > 0.f ? 0.25f/dd : 0.f;
    float conv = (acc[j][0]+acc[j][1]+acc[j][2]+acc[j][3])*dinv;
    float t = xv[j] + conv + biasv;
    float mu = wsum64(t) * (1.f/64.f);
    float dv = t - mu;
    float var = wsum64(dv*dv) * (1.f/64.f);
    hs[j] = dv * rsqrtf(var + LNEPS) * g1v + b1gv;
  }

  // folded FFN: 4 independent chains
  float a0 = bpv, a1 = bpv, a2 = bpv, a3 = bpv;
#pragma unroll
  for (int k = 0; k < 64; ++k){
    a0 = fmaf(__shfl(hs[0], k), w[k], a0);
    a1 = fmaf(__shfl(hs[1], k), w[k], a1);
    a2 = fmaf(__shfl(hs[2], k), w[k], a2);
    a3 = fmaf(__shfl(hs[3], k), w[k], a3);
  }

  float fa[4] = {a0, a1, a2, a3};
#pragma unroll
  for (int j = 0; j < 4; ++j){
    int n = nbase + j;
    float ffn = fa[j] > 0.f ? fa[j] : 0.01f*fa[j];
    float t2 = hs[j] + ffn;
    float mu2 = wsum64(t2) * (1.f/64.f);
    float dv2 = t2 - mu2;
    float var2 = wsum64(dv2*dv2) * (1.f/64.f);
    out[(size_t)n*DIM + lane] = dv2 * rsqrtf(var2 + LNEPS) * g2v + b2gv;
  }
}

extern "C" void kernel_launch(void* const* d_in, const int* in_sizes, int n_in,
                              void* d_out, int out_size, void* d_ws, size_t ws_size,
                              hipStream_t stream){
  const float* x     = (const float*)d_in[0];
  const int*   row   = (const int*)d_in[1];
  const int*   col   = (const int*)d_in[2];
  const float* val   = (const float*)d_in[3];
  const float* lin_w = (const float*)d_in[5];
  const float* att   = (const float*)d_in[6];
  const float* bias  = (const float*)d_in[7];
  const float* g1    = (const float*)d_in[8];
  const float* b1g   = (const float*)d_in[9];
  const float* g2    = (const float*)d_in[10];
  const float* b2g   = (const float*)d_in[11];
  const float* w1    = (const float*)d_in[12];
  const float* b1    = (const float*)d_in[13];
  const float* w2    = (const float*)d_in[14];
  const float* b2    = (const float*)d_in[15];
  float* out = (float*)d_out;
  float* ws  = (float*)d_ws;

  constexpr size_t E = N_EDGES, Nn = N_NODES;
  constexpr size_t o_ecnt   = 0;                   // E ints (zeroed)
  constexpr size_t o_ncnt   = o_ecnt + E;          // N ints
  constexpr size_t o_ecur   = o_ncnt + Nn;         // E ints
  constexpr size_t o_ncur   = o_ecur + E;          // N ints
  constexpr size_t o_colsum = o_ncur + Nn;         // E f
  constexpr size_t o_ddeg   = o_colsum + E;        // N f
  constexpr size_t ZEND     = o_ddeg + Nn;
  constexpr size_t o_colptr = ZEND;                // E+4 ints
  constexpr size_t o_rowptr = o_colptr + E + 4;    // N+4 ints
  constexpr size_t o_bsumE  = o_rowptr + Nn + 4;   // 256 ints
  constexpr size_t o_bsumN  = o_bsumE + 256;       // 256 ints
  constexpr size_t o_rvp    = (o_bsumN + 256 + 3) & ~(size_t)3;  // NNZ int4
  constexpr size_t o_wattx  = o_rvp + 4*(size_t)NNZ_;  // 256 f
  constexpr size_t o_watte  = o_wattx + 256;       // 256 f
  constexpr size_t o_Wf     = o_watte + 256;       // 4096 f
  constexpr size_t o_bp     = o_Wf + 4096;         // 64 f
  constexpr size_t o_snpe   = o_bp + 64;           // 8N f
  constexpr size_t o_alphaC = o_snpe + 8*Nn;       // 4*NNZ f (slow-path scratch)
  constexpr size_t o_ceal   = o_alphaC + 4*(size_t)NNZ_; // NNZ int4
  constexpr size_t o_xb     = o_ceal + 4*(size_t)NNZ_;   // N*64 bytes = 16N f
  constexpr size_t o_aggB   = o_xb + 16*Nn;        // E*256 ushort = 128E f
  constexpr size_t o_eo     = o_aggB + 128*E;      // E*64 uints = 64E f

  int*    ecnt   = (int*)(ws + o_ecnt);
  int*    ncnt   = (int*)(ws + o_ncnt);
  int*    ecur   = (int*)(ws + o_ecur);
  int*    ncur   = (int*)(ws + o_ncur);
  float*  colsum = ws + o_colsum;
  float*  ddeg   = ws + o_ddeg;
  int*    colptr = (int*)(ws + o_colptr);
  int*    rowptr = (int*)(ws + o_rowptr);
  int*    bsumE  = (int*)(ws + o_bsumE);
  int*    bsumN  = (int*)(ws + o_bsumN);
  int4*   rvp    = (int4*)(ws + o_rvp);
  float*  wattx  = ws + o_wattx;
  float*  watte  = ws + o_watte;
  float*  Wf     = ws + o_Wf;
  float*  bp     = ws + o_bp;
  float4* snpe   = (float4*)(ws + o_snpe);
  float4* alphaC = (float4*)(ws + o_alphaC);
  int4*   cealpha= (int4*)(ws + o_ceal);
  unsigned char* xb = (unsigned char*)(ws + o_xb);
  unsigned short* aggB = (unsigned short*)(ws + o_aggB);
  unsigned* eoT4 = (unsigned*)(ws + o_eo);

  hipMemsetAsync(ws, 0, ZEND*sizeof(float), stream);

  k_hist<<<(NNZ_+255)/256, 256, 0, stream>>>(row, col, val, ecnt, ncnt, colsum, ddeg);

  int nbE = (int)((E + 1023)/1024);   // 20
  int nbN = (int)((Nn + 1023)/1024);  // 98
  k_scanA2<<<nbE + nbN, 1024, 0, stream>>>(ecnt, colptr, bsumE, nbE, ncnt, rowptr, bsumN);
  k_scanB2<<<2, 256, 0, stream>>>(bsumE, nbE, colptr, bsumN, nbN, rowptr);
  k_scanC2<<<nbE + nbN, 1024, 0, stream>>>(colptr, bsumE, nbE, rowptr, bsumN);

  k_scatter<<<(NNZ_+255)/256, 256, 0, stream>>>(row, col, val, colptr, rowptr,
                                                ecur, ncur, rvp);

  k_watt<<<1, 256, 0, stream>>>(lin_w, att, wattx, watte);
  k_wfold<<<1, 256, 0, stream>>>(w1, w2, b1, b2, Wf, bp);
  k_pre<<<(int)((Nn+1)/2), 128, 0, stream>>>(x, wattx, watte, snpe, xb);
  k_softagg<<<(int)((E+1)/2), 128, 0, stream>>>(colptr, rvp, snpe, colsum, xb,
                                                alphaC, cealpha, aggB);
  k_eoT<<<(int)(E/16), 256, 0, stream>>>(aggB, lin_w, eoT4);
  k_final2<<<(int)(Nn/8), 128, 0, stream>>>(x, rowptr, cealpha, eoT4, ddeg,
                                            bias, g1, b1g, g2, b2g, Wf, bp, out);
}

// Round 15
// 441.653 us; speedup vs baseline: 1.0316x; 1.0023x over previous
//
#include <hip/hip_runtime.h>

#define N_NODES 100000
#define N_EDGES 20000
#define DIM 64
#define HEADS 4
#define NNZ_ 500000
#define LNEPS 1e-5f

__device__ __forceinline__ float wsum64(float v){
#pragma unroll
  for (int off = 32; off; off >>= 1) v += __shfl_xor(v, off);
  return v;
}
__device__ __forceinline__ float wmax64(float v){
#pragma unroll
  for (int off = 32; off; off >>= 1) v = fmaxf(v, __shfl_xor(v, off));
  return v;
}
__device__ __forceinline__ float lrelu2(float a){ return a > 0.f ? a : 0.2f*a; }

#define SCL 1.329227995784916e+36f   /* 2^120: folded into stored alphas */

// pack 2 floats -> 2 bf16 (RNE) in one uint (a in low16, b in high16)
__device__ __forceinline__ unsigned bfpack(float a, float b){
  unsigned ua = __float_as_uint(a), ub = __float_as_uint(b);
  ua += 0x7fffu + ((ua >> 16) & 1u);
  ub += 0x7fffu + ((ub >> 16) & 1u);
  return (ua >> 16) | (ub & 0xffff0000u);
}
__device__ __forceinline__ unsigned short bf16of(float f){
  unsigned u = __float_as_uint(f);
  u += 0x7fffu + ((u >> 16) & 1u);
  return (unsigned short)(u >> 16);
}
__device__ __forceinline__ float bfup(unsigned short s){
  return __uint_as_float(((unsigned)s) << 16);
}

// ---- manual fp8 e4m3 encode (RNE, flush<2^-6, clamp; never emits denormals/NaN) ----
__device__ __forceinline__ unsigned fp8of(float f){
  unsigned u = __float_as_uint(f);
  unsigned s = (u >> 24) & 0x80u;
  unsigned au = u & 0x7fffffffu;
  if (au < 0x3c800000u) return s;            // |f| < 2^-6 -> signed zero
  au += 0x7ffffu + ((au >> 20) & 1u);        // RNE to 3 mantissa bits
  unsigned e = (au >> 23) - 120u;            // rebias 127->7
  unsigned m = (au >> 20) & 7u;
  if (e > 15u){ e = 15u; m = 6u; }           // clamp
  return s | (e << 3) | m;
}
// cheap decode: returns true_value * 2^-120 (exact; no denormal inputs by construction)
__device__ __forceinline__ float fp8raw(unsigned b){
  return __uint_as_float(((b & 0x80u) << 24) | ((b & 0x7fu) << 20));
}

// ---- histogram + degree sums ----
__global__ __launch_bounds__(256) void k_hist(const int* __restrict__ row,
                                              const int* __restrict__ col,
                                              const float* __restrict__ val,
                                              int* __restrict__ ecnt, int* __restrict__ ncnt,
                                              float* __restrict__ colsum, float* __restrict__ ddeg){
  int i = blockIdx.x*256 + threadIdx.x;
  if (i >= NNZ_) return;
  int c = col[i], r = row[i];
  atomicAdd(&ecnt[c], 1);
  atomicAdd(&ncnt[r], 1);
  atomicAdd(&colsum[c], val[i]);
  atomicAdd(&ddeg[r], val[c]);   // reference: adj_val[adj_col[i]]
}

// ---- fused hierarchical scan over BOTH count arrays ----
__device__ __forceinline__ void scanA_body(const int* cnt, int* ptr, int* bsum,
                                           int n, int blk){
  __shared__ int wsums[16];
  int idx = blk*1024 + threadIdx.x;
  int lane = threadIdx.x & 63, wid = threadIdx.x >> 6;
  int v = (idx < n) ? cnt[idx] : 0;
  int s = v;
#pragma unroll
  for (int off = 1; off < 64; off <<= 1){
    int t = __shfl_up(s, off);
    if (lane >= off) s += t;
  }
  if (lane == 63) wsums[wid] = s;
  __syncthreads();
  if (wid == 0 && lane < 16){
    int ws = wsums[lane];
    int t = ws;
#pragma unroll
    for (int off = 1; off < 16; off <<= 1){
      int u = __shfl_up(t, off);
      if (lane >= off) t += u;
    }
    wsums[lane] = t - ws;
  }
  __syncthreads();
  if (idx < n) ptr[idx] = wsums[wid] + s - v;
  if (threadIdx.x == 1023) bsum[blk] = wsums[15] + s;
}

__global__ __launch_bounds__(1024) void k_scanA2(const int* __restrict__ ecnt,
                                                 int* __restrict__ colptr,
                                                 int* __restrict__ bsumE, int nbE,
                                                 const int* __restrict__ ncnt,
                                                 int* __restrict__ rowptr,
                                                 int* __restrict__ bsumN){
  int b = blockIdx.x;
  if (b < nbE) scanA_body(ecnt, colptr, bsumE, N_EDGES, b);
  else         scanA_body(ncnt, rowptr, bsumN, N_NODES, b - nbE);
}

__device__ __forceinline__ void scanB_body(int* bsum, int nb, int* ptr, int n){
  __shared__ int sh[256];
  int t = threadIdx.x;
  int v = (t < nb) ? bsum[t] : 0;
  sh[t] = v;
  __syncthreads();
  for (int off = 1; off < 256; off <<= 1){
    int u = (t >= off) ? sh[t-off] : 0;
    __syncthreads();
    sh[t] += u;
    __syncthreads();
  }
  if (t < nb) bsum[t] = sh[t] - v;
  if (t == nb-1) ptr[n] = sh[t];
}

__global__ __launch_bounds__(256) void k_scanB2(int* __restrict__ bsumE, int nbE,
                                                int* __restrict__ colptr,
                                                int* __restrict__ bsumN, int nbN,
                                                int* __restrict__ rowptr){
  if (blockIdx.x == 0) scanB_body(bsumE, nbE, colptr, N_EDGES);
  else                 scanB_body(bsumN, nbN, rowptr, N_NODES);
}

__global__ __launch_bounds__(1024) void k_scanC2(int* __restrict__ colptr,
                                                 const int* __restrict__ bsumE, int nbE,
                                                 int* __restrict__ rowptr,
                                                 const int* __restrict__ bsumN){
  int b = blockIdx.x;
  if (b < nbE){
    int idx = b*1024 + threadIdx.x;
    if (idx < N_EDGES) colptr[idx] += bsumE[b];
  } else {
    int idx = (b - nbE)*1024 + threadIdx.x;
    if (idx < N_NODES) rowptr[idx] += bsumN[b - nbE];
  }
}

// ---- scatter: ONE packed int4 {row, val, rpos, 0} per nnz in col-CSR order ----
__global__ __launch_bounds__(256) void k_scatter(const int* __restrict__ row,
                                                 const int* __restrict__ col,
                                                 const float* __restrict__ val,
                                                 const int* __restrict__ colptr,
                                                 const int* __restrict__ rowptr,
                                                 int* __restrict__ ecur, int* __restrict__ ncur,
                                                 int4* __restrict__ rvp){
  int i = blockIdx.x*256 + threadIdx.x;
  if (i >= NNZ_) return;
  int c = col[i], r = row[i];
  int p = atomicAdd(&ecur[c], 1);
  int q = atomicAdd(&ncur[r], 1);
  rvp[colptr[c] + p] = make_int4(r, __float_as_int(val[i]), rowptr[r] + q, 0);
}

// ---- folded attention vectors ----
__global__ __launch_bounds__(256) void k_watt(const float* __restrict__ lin_w,
                                              const float* __restrict__ att,
                                              float* __restrict__ wattx,
                                              float* __restrict__ watte){
  int j = threadIdx.x;           // j = h*64 + k
  int h = j >> 6;
  float sx = 0.f, se = 0.f;
#pragma unroll
  for (int d = 0; d < DIM; ++d){
    float w = lin_w[(h*DIM + d)*DIM + (j & 63)];
    sx = fmaf(att[h*2*DIM + d],       w, sx);
    se = fmaf(att[h*2*DIM + DIM + d], w, se);
  }
  wattx[j] = sx;
  watte[j] = se;
}

// ---- folded FFN: Wf = w2@w1, bp = w2@b1 + b2 ----
__global__ __launch_bounds__(256) void k_wfold(const float* __restrict__ w1,
                                               const float* __restrict__ w2,
                                               const float* __restrict__ b1,
                                               const float* __restrict__ b2,
                                               float* __restrict__ Wf,
                                               float* __restrict__ bp){
  int tid = threadIdx.x;
#pragma unroll
  for (int m = 0; m < 16; ++m){
    int idx = m*256 + tid;
    int o = idx >> 6, k = idx & 63;
    float s = 0.f;
#pragma unroll
    for (int i = 0; i < 64; ++i)
      s = fmaf(w2[o*64 + i], w1[i*64 + k], s);
    Wf[idx] = s;
  }
  if (tid < 64){
    float s = b2[tid];
#pragma unroll
    for (int i = 0; i < 64; ++i)
      s = fmaf(w2[tid*64 + i], b1[i], s);
    bp[tid] = s;
  }
}

// ---- per-node projections + fp8 copy of x ----
__global__ __launch_bounds__(128) void k_pre(const float* __restrict__ x,
                                             const float* __restrict__ wattx,
                                             const float* __restrict__ watte,
                                             float4* __restrict__ snpe,
                                             unsigned char* __restrict__ xb){
  int lane = threadIdx.x & 63, wid = threadIdx.x >> 6;
  int n = blockIdx.x*2 + wid;
  if (n >= N_NODES) return;
  float xv = x[(size_t)n*DIM + lane];
  xb[(size_t)n*DIM + lane] = (unsigned char)fp8of(xv);
  float s0 = wsum64(xv*wattx[lane]);
  float s1 = wsum64(xv*wattx[64+lane]);
  float s2 = wsum64(xv*wattx[128+lane]);
  float s3 = wsum64(xv*wattx[192+lane]);
  float p0 = wsum64(xv*watte[lane]);
  float p1 = wsum64(xv*watte[64+lane]);
  float p2 = wsum64(xv*watte[128+lane]);
  float p3 = wsum64(xv*watte[192+lane]);
  if (lane == 0){
    snpe[2*(size_t)n    ] = make_float4(s0,s1,s2,s3);
    snpe[2*(size_t)n + 1] = make_float4(p0,p1,p2,p3);
  }
}

// ---- merged: per-edge softmax + msg1 gather (fp8 x raw decode, scaled alphas) ----
__global__ __launch_bounds__(128) void k_softagg(const int* __restrict__ colptr,
                                                 const int4* __restrict__ rvp,
                                                 const float4* __restrict__ snpe,
                                                 const float* __restrict__ colsum,
                                                 const unsigned char* __restrict__ xb,
                                                 float4* __restrict__ alphaC,
                                                 int4* __restrict__ cealpha,
                                                 unsigned short* __restrict__ aggB){
  __shared__ float4 aSh[128];
  int lane = threadIdx.x & 63, wid = threadIdx.x >> 6;
  int e = blockIdx.x*2 + wid;
  if (e >= N_EDGES) return;
  int sb = __builtin_amdgcn_readfirstlane(colptr[e]);
  int cnt = __builtin_amdgcn_readfirstlane(colptr[e+1]) - sb;
  if (cnt == 0) return;
  float rcs = 1.0f / colsum[e];
  float acc0=0,acc1=0,acc2=0,acc3=0;

  if (cnt <= 64){
    bool act = lane < cnt;
    int r = 0, rp = 0; float v = 0.f;
    float4 snv = make_float4(0,0,0,0), p = make_float4(0,0,0,0);
    if (act){
      int4 m = rvp[sb+lane];
      r = m.x; v = __int_as_float(m.y); rp = m.z;
      snv = snpe[2*(size_t)r];
      p   = snpe[2*(size_t)r + 1];
    }
    float se0 = wsum64(v*p.x)*rcs, se1 = wsum64(v*p.y)*rcs,
          se2 = wsum64(v*p.z)*rcs, se3 = wsum64(v*p.w)*rcs;
    float t0 = act ? lrelu2(snv.x+se0) : -1e30f;
    float t1 = act ? lrelu2(snv.y+se1) : -1e30f;
    float t2 = act ? lrelu2(snv.z+se2) : -1e30f;
    float t3 = act ? lrelu2(snv.w+se3) : -1e30f;
    float m0 = wmax64(t0), m1 = wmax64(t1), m2 = wmax64(t2), m3 = wmax64(t3);
    float e0 = act ? __expf(t0-m0) : 0.f;
    float e1 = act ? __expf(t1-m1) : 0.f;
    float e2 = act ? __expf(t2-m2) : 0.f;
    float e3 = act ? __expf(t3-m3) : 0.f;
    float q0 = wsum64(e0), q1 = wsum64(e1), q2 = wsum64(e2), q3 = wsum64(e3);
    // SCALED alphas (×2^120): consumers multiply raw fp8 decodes
    float4 a = make_float4(e0/q0*SCL, e1/q1*SCL, e2/q2*SCL, e3/q3*SCL);
    if (act)
      cealpha[rp] = make_int4(e, (int)bfpack(a.x,a.y), (int)bfpack(a.z,a.w), 0);
    aSh[wid*64 + lane] = a;      // stage for uniform re-read (same wave)

    // gather: scalar meta + uniform LDS (scaled) alpha + raw fp8 x loads, 4-deep
    int k = 0;
    for (; k + 4 <= cnt; k += 4){
      int r0 = rvp[sb+k].x, r1 = rvp[sb+k+1].x, r2 = rvp[sb+k+2].x, r3 = rvp[sb+k+3].x;
      float4 a0 = aSh[wid*64+k], a1 = aSh[wid*64+k+1],
             a2 = aSh[wid*64+k+2], a3 = aSh[wid*64+k+3];
      float x0 = fp8raw((unsigned)xb[(size_t)r0*DIM + lane]);
      float x1 = fp8raw((unsigned)xb[(size_t)r1*DIM + lane]);
      float x2 = fp8raw((unsigned)xb[(size_t)r2*DIM + lane]);
      float x3 = fp8raw((unsigned)xb[(size_t)r3*DIM + lane]);
      acc0 = fmaf(a0.x, x0, acc0); acc1 = fmaf(a0.y, x0, acc1);
      acc2 = fmaf(a0.z, x0, acc2); acc3 = fmaf(a0.w, x0, acc3);
      acc0 = fmaf(a1.x, x1, acc0); acc1 = fmaf(a1.y, x1, acc1);
      acc2 = fmaf(a1.z, x1, acc2); acc3 = fmaf(a1.w, x1, acc3);
      acc0 = fmaf(a2.x, x2, acc0); acc1 = fmaf(a2.y, x2, acc1);
      acc2 = fmaf(a2.z, x2, acc2); acc3 = fmaf(a2.w, x2, acc3);
      acc0 = fmaf(a3.x, x3, acc0); acc1 = fmaf(a3.y, x3, acc1);
      acc2 = fmaf(a3.z, x3, acc2); acc3 = fmaf(a3.w, x3, acc3);
    }
    for (; k < cnt; ++k){
      int r0 = rvp[sb+k].x;
      float4 a0 = aSh[wid*64+k];
      float x0 = fp8raw((unsigned)xb[(size_t)r0*DIM + lane]);
      acc0 = fmaf(a0.x, x0, acc0); acc1 = fmaf(a0.y, x0, acc1);
      acc2 = fmaf(a0.z, x0, acc2); acc3 = fmaf(a0.w, x0, acc3);
    }
  } else {
    // ---- rare slow path (cnt > 64): multi-pass via alphaC scratch (scaled) ----
    int s = sb;
    float a0=0,a1=0,a2=0,a3=0;
    for (int base = 0; base < cnt; base += 64){
      int j = s + base + lane;
      if (base + lane < cnt){
        int4 m = rvp[j];
        float v = __int_as_float(m.y);
        float4 p = snpe[2*(size_t)m.x + 1];
        a0 = fmaf(v,p.x,a0); a1 = fmaf(v,p.y,a1); a2 = fmaf(v,p.z,a2); a3 = fmaf(v,p.w,a3);
      }
    }
    float se0 = wsum64(a0)*rcs, se1 = wsum64(a1)*rcs, se2 = wsum64(a2)*rcs, se3 = wsum64(a3)*rcs;
    float m0=-1e30f,m1=-1e30f,m2=-1e30f,m3=-1e30f;
    for (int base = 0; base < cnt; base += 64){
      int j = s + base + lane;
      if (base + lane < cnt){
        float4 snv = snpe[2*(size_t)rvp[j].x];
        m0 = fmaxf(m0, lrelu2(snv.x+se0)); m1 = fmaxf(m1, lrelu2(snv.y+se1));
        m2 = fmaxf(m2, lrelu2(snv.z+se2)); m3 = fmaxf(m3, lrelu2(snv.w+se3));
      }
    }
    m0 = wmax64(m0); m1 = wmax64(m1); m2 = wmax64(m2); m3 = wmax64(m3);
    float q0=0,q1=0,q2=0,q3=0;
    for (int base = 0; base < cnt; base += 64){
      int j = s + base + lane;
      if (base + lane < cnt){
        float4 snv = snpe[2*(size_t)rvp[j].x];
        float e0 = __expf(lrelu2(snv.x+se0)-m0), e1 = __expf(lrelu2(snv.y+se1)-m1);
        float e2 = __expf(lrelu2(snv.z+se2)-m2), e3 = __expf(lrelu2(snv.w+se3)-m3);
        q0+=e0; q1+=e1; q2+=e2; q3+=e3;
        alphaC[j] = make_float4(e0,e1,e2,e3);
      }
    }
    q0 = wsum64(q0); q1 = wsum64(q1); q2 = wsum64(q2); q3 = wsum64(q3);
    float r0 = SCL/q0, r1 = SCL/q1, r2 = SCL/q2, r3 = SCL/q3;
    for (int base = 0; base < cnt; base += 64){
      int j = s + base + lane;
      if (base + lane < cnt){
        float4 av = alphaC[j];
        av = make_float4(av.x*r0, av.y*r1, av.z*r2, av.w*r3);   // scaled
        alphaC[j] = av;
        cealpha[rvp[j].z] = make_int4(e, (int)bfpack(av.x,av.y), (int)bfpack(av.z,av.w), 0);
      }
    }
    for (int k = 0; k < cnt; ++k){
      int rj = rvp[sb+k].x;          // scalar load
      float4 al = alphaC[sb+k];      // scalar load (scaled)
      float xv = fp8raw((unsigned)xb[(size_t)rj*DIM + lane]);
      acc0 = fmaf(al.x, xv, acc0); acc1 = fmaf(al.y, xv, acc1);
      acc2 = fmaf(al.z, xv, acc2); acc3 = fmaf(al.w, xv, acc3);
    }
  }

  float binv = 1.0f/(float)cnt;
  size_t b = (size_t)e*256;
  aggB[b       + lane] = bf16of(acc0*binv);
  aggB[b +  64 + lane] = bf16of(acc1*binv);
  aggB[b + 128 + lane] = bf16of(acc2*binv);
  aggB[b + 192 + lane] = bf16of(acc3*binv);
}

// ---- per-edge lin_w transform (bf16 in), head-interleaved FP8 out: eoT4[e][d]=uint(4 heads)
__global__ __launch_bounds__(256) void k_eoT(const unsigned short* __restrict__ aggB,
                                             const float* __restrict__ lin_w,
                                             unsigned* __restrict__ eoT4){
  __shared__ float L[16*260];
  int lane = threadIdx.x & 63, h = threadIdx.x >> 6;
  float w[64];
  const float4* wr = (const float4*)(lin_w + ((size_t)h*64 + lane)*64);
#pragma unroll
  for (int k = 0; k < 16; ++k){
    float4 t = wr[k];
    w[4*k] = t.x; w[4*k+1] = t.y; w[4*k+2] = t.z; w[4*k+3] = t.w;
  }
  int e0 = blockIdx.x*16;
#pragma unroll
  for (int el = 0; el < 16; el += 4){
    float av0 = bfup(aggB[(size_t)(e0+el  )*256 + h*64 + lane]);
    float av1 = bfup(aggB[(size_t)(e0+el+1)*256 + h*64 + lane]);
    float av2 = bfup(aggB[(size_t)(e0+el+2)*256 + h*64 + lane]);
    float av3 = bfup(aggB[(size_t)(e0+el+3)*256 + h*64 + lane]);
    float o0=0.f, o1=0.f, o2=0.f, o3=0.f;
#pragma unroll
    for (int k = 0; k < 64; ++k){
      float wk = w[k];
      o0 = fmaf(__shfl(av0, k), wk, o0);
      o1 = fmaf(__shfl(av1, k), wk, o1);
      o2 = fmaf(__shfl(av2, k), wk, o2);
      o3 = fmaf(__shfl(av3, k), wk, o3);
    }
    L[(el  )*260 + lane*4 + h] = o0;
    L[(el+1)*260 + lane*4 + h] = o1;
    L[(el+2)*260 + lane*4 + h] = o2;
    L[(el+3)*260 + lane*4 + h] = o3;
  }
  __syncthreads();
  int tid = threadIdx.x;
#pragma unroll
  for (int p = 0; p < 4; ++p){
    int el = p*4 + (tid >> 6);
    int l = tid & 63;
    const float* Lr = &L[el*260 + l*4];
    unsigned v = fp8of(Lr[0]) | (fp8of(Lr[1]) << 8) |
                 (fp8of(Lr[2]) << 16) | (fp8of(Lr[3]) << 24);
    eoT4[(size_t)(e0+el)*64 + l] = v;
  }
}

// in-place masked raw decodes (value × 2^-120); alphas are pre-scaled ×2^120
#define ACC4(J, V, M) { \
  float u0 = __uint_as_float((((V) & 0x80u) << 24)       | (((V) & 0x7fu) << 20)); \
  float u1 = __uint_as_float((((V) & 0x8000u) << 16)     | (((V) & 0x7f00u) << 12)); \
  float u2 = __uint_as_float((((V) & 0x800000u) << 8)    | (((V) & 0x7f0000u) << 4)); \
  float u3 = __uint_as_float(((V) & 0x80000000u)         | (((V) & 0x7f000000u) >> 4)); \
  float ax = __uint_as_float(((unsigned)(M).y) << 16); \
  float ay = __uint_as_float(((unsigned)(M).y) & 0xffff0000u); \
  float az = __uint_as_float(((unsigned)(M).z) << 16); \
  float aw = __uint_as_float(((unsigned)(M).z) & 0xffff0000u); \
  acc[J][0] = fmaf(u0, ax, acc[J][0]); \
  acc[J][1] = fmaf(u1, ay, acc[J][1]); \
  acc[J][2] = fmaf(u2, az, acc[J][2]); \
  acc[J][3] = fmaf(u3, aw, acc[J][3]); }

#define SEG(J, KB, KE) do { \
    int k = (KB); \
    for (; k + 4 <= (KE); k += 4){ \
      int4 m0 = cealpha[k], m1 = cealpha[k+1], m2 = cealpha[k+2], m3 = cealpha[k+3]; \
      unsigned v0 = eoT4[(size_t)m0.x*64 + lane]; \
      unsigned v1 = eoT4[(size_t)m1.x*64 + lane]; \
      unsigned v2 = eoT4[(size_t)m2.x*64 + lane]; \
      unsigned v3 = eoT4[(size_t)m3.x*64 + lane]; \
      ACC4(J, v0, m0); ACC4(J, v1, m1); ACC4(J, v2, m2); ACC4(J, v3, m3); \
    } \
    for (; k < (KE); ++k){ \
      int4 m0 = cealpha[k]; \
      unsigned v0 = eoT4[(size_t)m0.x*64 + lane]; \
      ACC4(J, v0, m0); \
    } \
  } while(0)

// ---- fused: msg2 gather (fp8 table, scaled-alpha meta) + LN1 + folded FFN + LN2 ----
__global__ __launch_bounds__(128) void k_final2(const float* __restrict__ x,
                                                const int* __restrict__ rowptr,
                                                const int4* __restrict__ cealpha,
                                                const unsigned* __restrict__ eoT4,
                                                const float* __restrict__ ddeg,
                                                const float* __restrict__ bias,
                                                const float* __restrict__ g1,
                                                const float* __restrict__ b1g,
                                                const float* __restrict__ g2,
                                                const float* __restrict__ b2g,
                                                const float* __restrict__ Wf,
                                                const float* __restrict__ bp,
                                                float* __restrict__ out){
  int lane = threadIdx.x & 63, wid = threadIdx.x >> 6;
  int nbase = blockIdx.x*8 + wid*4;
  int q0 = __builtin_amdgcn_readfirstlane(rowptr[nbase]);
  int q1 = __builtin_amdgcn_readfirstlane(rowptr[nbase+1]);
  int q2 = __builtin_amdgcn_readfirstlane(rowptr[nbase+2]);
  int q3 = __builtin_amdgcn_readfirstlane(rowptr[nbase+3]);
  int q4 = __builtin_amdgcn_readfirstlane(rowptr[nbase+4]);

  // early independent loads (overlap with gather issue)
  float xv[4];
#pragma unroll
  for (int j = 0; j < 4; ++j) xv[j] = x[(size_t)(nbase+j)*DIM + lane];
  float dd0 = ddeg[nbase], dd1 = ddeg[nbase+1], dd2 = ddeg[nbase+2], dd3 = ddeg[nbase+3];

  float acc[4][4];
#pragma unroll
  for (int j = 0; j < 4; ++j)
#pragma unroll
    for (int h = 0; h < 4; ++h) acc[j][h] = 0.f;

  SEG(0, q0, q1);
  SEG(1, q1, q2);
  SEG(2, q2, q3);
  SEG(3, q3, q4);

  // FFN weights + LN params (loaded after gather)
  float w[64];
  const float4* wr = (const float4*)(Wf + (size_t)lane*64);
#pragma unroll
  for (int k = 0; k < 16; ++k){
    float4 t = wr[k];
    w[4*k] = t.x; w[4*k+1] = t.y; w[4*k+2] = t.z; w[4*k+3] = t.w;
  }
  float biasv = bias[lane], bpv = bp[lane];
  float g1v = g1[lane], b1gv = b1g[lane], g2v = g2[lane], b2gv = b2g[lane];

  // LN1 per node
  float ddv[4] = {dd0, dd1, dd2, dd3};
  float hs[4];
#pragma unroll
  for (int j = 0; j < 4; ++j){
    float dd = ddv[j];
    float dinv = dd > 0.f ? 0.25f/dd : 0.f;
    float conv = (acc[j][0]+acc[j][1]+acc[j][2]+acc[j][3])*dinv;
    float t = xv[j] + conv + biasv;
    float mu = wsum64(t) * (1.f/64.f);
    float dv = t - mu;
    float var = wsum64(dv*dv) * (1.f/64.f);
    hs[j] = dv * rsqrtf(var + LNEPS) * g1v + b1gv;
  }

  // folded FFN: 4 independent chains
  float a0 = bpv, a1 = bpv, a2 = bpv, a3 = bpv;
#pragma unroll
  for (int k = 0; k < 64; ++k){
    a0 = fmaf(__shfl(hs[0], k), w[k], a0);
    a1 = fmaf(__shfl(hs[1], k), w[k], a1);
    a2 = fmaf(__shfl(hs[2], k), w[k], a2);
    a3 = fmaf(__shfl(hs[3], k), w[k], a3);
  }

  float fa[4] = {a0, a1, a2, a3};
#pragma unroll
  for (int j = 0; j < 4; ++j){
    int n = nbase + j;
    float ffn = fa[j] > 0.f ? fa[j] : 0.01f*fa[j];
    float t2 = hs[j] + ffn;
    float mu2 = wsum64(t2) * (1.f/64.f);
    float dv2 = t2 - mu2;
    float var2 = wsum64(dv2*dv2) * (1.f/64.f);
    out[(size_t)n*DIM + lane] = dv2 * rsqrtf(var2 + LNEPS) * g2v + b2gv;
  }
}

extern "C" void kernel_launch(void* const* d_in, const int* in_sizes, int n_in,
                              void* d_out, int out_size, void* d_ws, size_t ws_size,
                              hipStream_t stream){
  const float* x     = (const float*)d_in[0];
  const int*   row   = (const int*)d_in[1];
  const int*   col   = (const int*)d_in[2];
  const float* val   = (const float*)d_in[3];
  const float* lin_w = (const float*)d_in[5];
  const float* att   = (const float*)d_in[6];
  const float* bias  = (const float*)d_in[7];
  const float* g1    = (const float*)d_in[8];
  const float* b1g   = (const float*)d_in[9];
  const float* g2    = (const float*)d_in[10];
  const float* b2g   = (const float*)d_in[11];
  const float* w1    = (const float*)d_in[12];
  const float* b1    = (const float*)d_in[13];
  const float* w2    = (const float*)d_in[14];
  const float* b2    = (const float*)d_in[15];
  float* out = (float*)d_out;
  float* ws  = (float*)d_ws;

  constexpr size_t E = N_EDGES, Nn = N_NODES;
  constexpr size_t o_ecnt   = 0;                   // E ints (zeroed)
  constexpr size_t o_ncnt   = o_ecnt + E;          // N ints
  constexpr size_t o_ecur   = o_ncnt + Nn;         // E ints
  constexpr size_t o_ncur   = o_ecur + E;          // N ints
  constexpr size_t o_colsum = o_ncur + Nn;         // E f
  constexpr size_t o_ddeg   = o_colsum + E;        // N f
  constexpr size_t ZEND     = o_ddeg + Nn;
  constexpr size_t o_colptr = ZEND;                // E+4 ints
  constexpr size_t o_rowptr = o_colptr + E + 4;    // N+4 ints
  constexpr size_t o_bsumE  = o_rowptr + Nn + 4;   // 256 ints
  constexpr size_t o_bsumN  = o_bsumE + 256;       // 256 ints
  constexpr size_t o_rvp    = (o_bsumN + 256 + 3) & ~(size_t)3;  // NNZ int4
  constexpr size_t o_wattx  = o_rvp + 4*(size_t)NNZ_;  // 256 f
  constexpr size_t o_watte  = o_wattx + 256;       // 256 f
  constexpr size_t o_Wf     = o_watte + 256;       // 4096 f
  constexpr size_t o_bp     = o_Wf + 4096;         // 64 f
  constexpr size_t o_snpe   = o_bp + 64;           // 8N f
  constexpr size_t o_alphaC = o_snpe + 8*Nn;       // 4*NNZ f (slow-path scratch)
  constexpr size_t o_ceal   = o_alphaC + 4*(size_t)NNZ_; // NNZ int4
  constexpr size_t o_xb     = o_ceal + 4*(size_t)NNZ_;   // N*64 bytes = 16N f
  constexpr size_t o_aggB   = o_xb + 16*Nn;        // E*256 ushort = 128E f
  constexpr size_t o_eo     = o_aggB + 128*E;      // E*64 uints = 64E f

  int*    ecnt   = (int*)(ws + o_ecnt);
  int*    ncnt   = (int*)(ws + o_ncnt);
  int*    ecur   = (int*)(ws + o_ecur);
  int*    ncur   = (int*)(ws + o_ncur);
  float*  colsum = ws + o_colsum;
  float*  ddeg   = ws + o_ddeg;
  int*    colptr = (int*)(ws + o_colptr);
  int*    rowptr = (int*)(ws + o_rowptr);
  int*    bsumE  = (int*)(ws + o_bsumE);
  int*    bsumN  = (int*)(ws + o_bsumN);
  int4*   rvp    = (int4*)(ws + o_rvp);
  float*  wattx  = ws + o_wattx;
  float*  watte  = ws + o_watte;
  float*  Wf     = ws + o_Wf;
  float*  bp     = ws + o_bp;
  float4* snpe   = (float4*)(ws + o_snpe);
  float4* alphaC = (float4*)(ws + o_alphaC);
  int4*   cealpha= (int4*)(ws + o_ceal);
  unsigned char* xb = (unsigned char*)(ws + o_xb);
  unsigned short* aggB = (unsigned short*)(ws + o_aggB);
  unsigned* eoT4 = (unsigned*)(ws + o_eo);

  hipMemsetAsync(ws, 0, ZEND*sizeof(float), stream);

  k_hist<<<(NNZ_+255)/256, 256, 0, stream>>>(row, col, val, ecnt, ncnt, colsum, ddeg);

  int nbE = (int)((E + 1023)/1024);   // 20
  int nbN = (int)((Nn + 1023)/1024);  // 98
  k_scanA2<<<nbE + nbN, 1024, 0, stream>>>(ecnt, colptr, bsumE, nbE, ncnt, rowptr, bsumN);
  k_scanB2<<<2, 256, 0, stream>>>(bsumE, nbE, colptr, bsumN, nbN, rowptr);
  k_scanC2<<<nbE + nbN, 1024, 0, stream>>>(colptr, bsumE, nbE, rowptr, bsumN);

  k_scatter<<<(NNZ_+255)/256, 256, 0, stream>>>(row, col, val, colptr, rowptr,
                                                ecur, ncur, rvp);

  k_watt<<<1, 256, 0, stream>>>(lin_w, att, wattx, watte);
  k_wfold<<<1, 256, 0, stream>>>(w1, w2, b1, b2, Wf, bp);
  k_pre<<<(int)((Nn+1)/2), 128, 0, stream>>>(x, wattx, watte, snpe, xb);
  k_softagg<<<(int)((E+1)/2), 128, 0, stream>>>(colptr, rvp, snpe, colsum, xb,
                                                alphaC, cealpha, aggB);
  k_eoT<<<(int)(E/16), 256, 0, stream>>>(aggB, lin_w, eoT4);
  k_final2<<<(int)(Nn/8), 128, 0, stream>>>(x, rowptr, cealpha, eoT4, ddeg,
                                            bias, g1, b1g, g2, b2g, Wf, bp, out);
}